// Round 6
// baseline (56.480 us; speedup 1.0000x reference)
//
#include <hip/hip_runtime.h>

// NIoULoss_pixel: B=8, N=8, H=W=512. One-pass fused reduction.
// R6: mask loads go global->LDS via __builtin_amdgcn_global_load_lds (width=16)
// so the payload costs ZERO VGPRs — the register allocator can no longer
// serialize the batch (the R2-R5 failure mode, VGPR stuck ~50-100).
// Drain with counted s_waitcnt vmcnt(14..0): mask n processes while 14-2n
// loads are still in flight. Each wave stages/reads only its own 1KB slice
// (global_load_lds writes wave-uniform base + lane*16), so no barrier in the
// hot path. Stage LDS (64KB) is aliased with the transpose-reduce epilogue.

constexpr int Bc  = 8;
constexpr int Nc  = 8;
constexpr int HWc = 512 * 512;
constexpr int PAD = 16;               // floats per counter slot (64 B line)
constexpr float EPSc = 1e-6f;

// 256 blocks per image, 256 threads/block, 1 quad (4 pixels) per thread.
__global__ __launch_bounds__(256, 2) void niou_partial(
    const float* __restrict__ pd, const float* __restrict__ gt,
    const int* __restrict__ pmask, const int* __restrict__ gmask,
    float* __restrict__ ws /* [B][40][PAD] */)
{
    __shared__ int4 smem4[4096];      // 64 KiB: 16 stage tiles of 4 KiB each

    const int b    = blockIdx.x >> 8;
    const int blk  = blockIdx.x & 255;
    const int tid  = threadIdx.x;
    const int lane = tid & 63;
    const int wv   = tid >> 6;
    constexpr int HW4 = HWc / 4;
    const int quad = blk * 256 + tid;
    const size_t p = (size_t)quad * 4;

    // ---- rgbo loads to registers (issued first: oldest in vmcnt queue) ----
    const float4* pd4 = reinterpret_cast<const float4*>(pd + (size_t)b * 4 * HWc + p);
    const float4* gt4 = reinterpret_cast<const float4*>(gt + (size_t)b * 4 * HWc + p);
    float4 pv[4], gv[4];
#pragma unroll
    for (int c = 0; c < 4; ++c) pv[c] = pd4[c * HW4];
#pragma unroll
    for (int c = 0; c < 4; ++c) gv[c] = gt4[c * HW4];
    __builtin_amdgcn_sched_barrier(0);

    // ---- stage all 16 mask tiles global->LDS (no dest VGPRs) ----
    // slot(n,tensor): pm -> 2n, gm -> 2n+1; wave wv's slice at [slot*256 + wv*64]
    const int* pmB = pmask + (size_t)b * Nc * HWc + p;   // per-lane global addr
    const int* gmB = gmask + (size_t)b * Nc * HWc + p;
#pragma unroll
    for (int n = 0; n < Nc; ++n) {
        __builtin_amdgcn_global_load_lds(
            (const __attribute__((address_space(1))) void*)(pmB + (size_t)n * HWc),
            (__attribute__((address_space(3))) void*)&smem4[(2 * n) * 256 + wv * 64],
            16, 0, 0);
        __builtin_amdgcn_global_load_lds(
            (const __attribute__((address_space(1))) void*)(gmB + (size_t)n * HWc),
            (__attribute__((address_space(3))) void*)&smem4[(2 * n + 1) * 256 + wv * 64],
            16, 0, 0);
    }
    __builtin_amdgcn_sched_barrier(0);   // all 8+16 VMEM ops now issued

    // ---- per-pixel quantities (compiler waits only on the 8 rgbo loads) ----
    float dn[4], po[4], go[4];
    {
        float dx, dy, dz;
        dx = pv[0].x - gv[0].x; dy = pv[1].x - gv[1].x; dz = pv[2].x - gv[2].x;
        dn[0] = sqrtf(dx*dx + dy*dy + dz*dz); po[0] = rintf(pv[3].x); go[0] = rintf(gv[3].x);
        dx = pv[0].y - gv[0].y; dy = pv[1].y - gv[1].y; dz = pv[2].y - gv[2].y;
        dn[1] = sqrtf(dx*dx + dy*dy + dz*dz); po[1] = rintf(pv[3].y); go[1] = rintf(gv[3].y);
        dx = pv[0].z - gv[0].z; dy = pv[1].z - gv[1].z; dz = pv[2].z - gv[2].z;
        dn[2] = sqrtf(dx*dx + dy*dy + dz*dz); po[2] = rintf(pv[3].z); go[2] = rintf(gv[3].z);
        dx = pv[0].w - gv[0].w; dy = pv[1].w - gv[1].w; dz = pv[2].w - gv[2].w;
        dn[3] = sqrtf(dx*dx + dy*dy + dz*dz); po[3] = rintf(pv[3].w); go[3] = rintf(gv[3].w);
    }

    // acc[n]: {sim_sum, inter, gt_sum, pd_xor_sum}; count via ballot
    float acc[Nc][4];
    int   wcnt[Nc];
#pragma unroll
    for (int n = 0; n < Nc; ++n) {
        wcnt[n] = 0;
#pragma unroll
        for (int q = 0; q < 4; ++q) acc[n][q] = 0.f;
    }

    // ---- drain mask tiles with counted vmcnt: tile n ready at 14-2n left ----
#define PROC(n_, cnt_) do {                                                   \
        asm volatile("s_waitcnt vmcnt(" #cnt_ ")" ::: "memory");              \
        __builtin_amdgcn_sched_barrier(0);                                    \
        const int4 pmv = smem4[(2 * (n_)) * 256 + wv * 64 + lane];            \
        const int4 gmv = smem4[(2 * (n_) + 1) * 256 + wv * 64 + lane];        \
        const int pmx[4] = {pmv.x, pmv.y, pmv.z, pmv.w};                      \
        const int gmx[4] = {gmv.x, gmv.y, gmv.z, gmv.w};                      \
        _Pragma("unroll")                                                     \
        for (int j = 0; j < 4; ++j) {                                         \
            const bool P = pmx[j] != 0;                                       \
            const bool G = gmx[j] != 0;                                       \
            wcnt[n_] += __popcll(__ballot(P));                                \
            acc[n_][0] += P ? dn[j] : 0.f;                                    \
            acc[n_][1] += (P && G)  ? po[j] : 0.f;                            \
            acc[n_][2] += G ? go[j] : 0.f;                                    \
            acc[n_][3] += (P && !G) ? po[j] : 0.f;                            \
        }                                                                     \
    } while (0)

    PROC(0, 14); PROC(1, 12); PROC(2, 10); PROC(3, 8);
    PROC(4, 6);  PROC(5, 4);  PROC(6, 2);  PROC(7, 0);
#undef PROC

    // ---- LDS-transpose block reduction (aliases the stage LDS) ----
    __syncthreads();   // all waves done reading stage slices before overwrite

    float (*tr)[33] = reinterpret_cast<float(*)[33]>(smem4);            // 33792 B
    float (*part)   = reinterpret_cast<float*>(
                          reinterpret_cast<char*>(smem4) + 33792);      // 4*32 floats
    float (*cpart)  = reinterpret_cast<float*>(
                          reinterpret_cast<char*>(smem4) + 33792 + 512);// 4*8 floats

#pragma unroll
    for (int qi = 0; qi < 32; ++qi) tr[tid][qi] = acc[qi >> 2][qi & 3];
    if (lane == 0) {
#pragma unroll
        for (int n = 0; n < Nc; ++n) cpart[wv * Nc + n] = (float)wcnt[n];
    }
    __syncthreads();

    {
        const int q    = tid & 31;   // quantity
        const int half = tid >> 5;   // chunk of 32 rows
        float s = 0.f;
#pragma unroll
        for (int k = 0; k < 32; ++k) s += tr[half * 32 + k][q];
        s += __shfl_xor(s, 32, 64);          // combine the two halves in this wave
        if ((tid & 32) == 0) part[(tid >> 6) * 32 + q] = s;
    }
    __syncthreads();

    if (tid < 32) {
        const float v = part[0 * 32 + tid] + part[1 * 32 + tid] +
                        part[2 * 32 + tid] + part[3 * 32 + tid];
        const int n = tid >> 2, qq = tid & 3;
        const int slot = n * 5 + (qq == 0 ? 0 : qq + 1);
        atomicAdd(&ws[(b * 40 + slot) * PAD], v);
    } else if (tid >= 64 && tid < 64 + Nc) {
        const int n = tid - 64;
        const float c = cpart[0 * Nc + n] + cpart[1 * Nc + n] +
                        cpart[2 * Nc + n] + cpart[3 * Nc + n];
        atomicAdd(&ws[(b * 40 + n * 5 + 1) * PAD], c);
    }
}

__global__ __launch_bounds__(64) void niou_final(
    const float* __restrict__ ws, float* __restrict__ out)
{
    const int t = threadIdx.x;   // 0..63 == b*8+n
    const float* w = ws + (size_t)t * 5 * PAD;
    const float sim   = w[0 * PAD];
    const float cnt   = w[1 * PAD];
    const float inter = w[2 * PAD];
    const float gts   = w[3 * PAD];
    const float xo    = w[4 * PAD];
    const float punish = sim / (cnt + EPSc);
    const float iou    = inter / (gts + xo + EPSc);
    float term = 1.0f - iou + punish;
#pragma unroll
    for (int off = 32; off; off >>= 1) term += __shfl_xor(term, off, 64);
    if (t == 0) out[0] = term * (1.0f / 64.0f);
}

extern "C" void kernel_launch(void* const* d_in, const int* in_sizes, int n_in,
                              void* d_out, int out_size, void* d_ws, size_t ws_size,
                              hipStream_t stream) {
    const float* pd_rgbo = (const float*)d_in[0];
    const float* gt_rgbo = (const float*)d_in[1];
    const int*   pd_mask = (const int*)d_in[2];
    const int*   gt_mask = (const int*)d_in[3];
    float* out = (float*)d_out;
    float* ws  = (float*)d_ws;

    hipMemsetAsync(ws, 0, Bc * 40 * PAD * sizeof(float), stream);
    niou_partial<<<Bc * 256, 256, 0, stream>>>(pd_rgbo, gt_rgbo, pd_mask, gt_mask, ws);
    niou_final<<<1, 64, 0, stream>>>(ws, out);
}

// Round 7
// 46.446 us; speedup vs baseline: 1.2160x; 1.2160x over previous
//
#include <hip/hip_runtime.h>

// NIoULoss_pixel: B=8, N=8, H=W=512. One-pass fused reduction.
// R7: ALL 24 global loads issued as asm-volatile global_load_dwordx4 in fixed
// program order (compiler provably refused to batch them R2-R6: VGPR stuck
// 48-100 => ~0.6 loads in flight/wave => 44us latency plateau). Drain with
// counted s_waitcnt vmcnt(N)+sched_barrier(0): vmcnt(16) frees the dn-compute
// with all 16 mask loads still flying; vmcnt(14-2n) per plane n.
// xor accumulated as s=P?po:0 (xor = s - inter, applied in niou_final).

constexpr int Bc  = 8;
constexpr int Nc  = 8;
constexpr int HWc = 512 * 512;
constexpr int PAD = 16;               // floats per counter slot (64 B line)
constexpr float EPSc = 1e-6f;

__device__ __forceinline__ float4 gload_f4(const float* a) {
    float4 r;
    asm volatile("global_load_dwordx4 %0, %1, off" : "=v"(r) : "v"(a) : "memory");
    return r;
}
__device__ __forceinline__ int4 gload_i4(const int* a) {
    int4 r;
    asm volatile("global_load_dwordx4 %0, %1, off" : "=v"(r) : "v"(a) : "memory");
    return r;
}
#define WAITV(n_) do {                                                   \
        asm volatile("s_waitcnt vmcnt(" #n_ ")" ::: "memory");           \
        __builtin_amdgcn_sched_barrier(0);                               \
    } while (0)

// 256 blocks per image, 256 threads/block, 1 quad (4 pixels) per thread.
__global__ __launch_bounds__(256, 2) void niou_partial(
    const float* __restrict__ pd, const float* __restrict__ gt,
    const int* __restrict__ pmask, const int* __restrict__ gmask,
    float* __restrict__ ws /* [B][40][PAD] */)
{
    const int b    = blockIdx.x >> 8;
    const int blk  = blockIdx.x & 255;
    const int tid  = threadIdx.x;
    const int lane = tid & 63;
    const int wv   = tid >> 6;
    const size_t p = (size_t)(blk * 256 + tid) * 4;

    const float* pdB = pd + (size_t)b * 4 * HWc + p;
    const float* gtB = gt + (size_t)b * 4 * HWc + p;
    const int*   pmB = pmask + (size_t)b * Nc * HWc + p;
    const int*   gmB = gmask + (size_t)b * Nc * HWc + p;

    // ---- 24 loads, fixed order: 8 rgbo first, then 16 masks ----
    float4 pv[4], gv[4];
    int4   pmv[Nc], gmv[Nc];
#pragma unroll
    for (int c = 0; c < 4; ++c) pv[c] = gload_f4(pdB + (size_t)c * HWc);
#pragma unroll
    for (int c = 0; c < 4; ++c) gv[c] = gload_f4(gtB + (size_t)c * HWc);
#pragma unroll
    for (int n = 0; n < Nc; ++n) {
        pmv[n] = gload_i4(pmB + (size_t)n * HWc);
        gmv[n] = gload_i4(gmB + (size_t)n * HWc);
    }

    // ---- rgbo ready; 16 mask loads still in flight ----
    WAITV(16);
    float dn[4], po[4], go[4];
    {
        float dx, dy, dz;
        dx = pv[0].x - gv[0].x; dy = pv[1].x - gv[1].x; dz = pv[2].x - gv[2].x;
        dn[0] = sqrtf(dx*dx + dy*dy + dz*dz); po[0] = rintf(pv[3].x); go[0] = rintf(gv[3].x);
        dx = pv[0].y - gv[0].y; dy = pv[1].y - gv[1].y; dz = pv[2].y - gv[2].y;
        dn[1] = sqrtf(dx*dx + dy*dy + dz*dz); po[1] = rintf(pv[3].y); go[1] = rintf(gv[3].y);
        dx = pv[0].z - gv[0].z; dy = pv[1].z - gv[1].z; dz = pv[2].z - gv[2].z;
        dn[2] = sqrtf(dx*dx + dy*dy + dz*dz); po[2] = rintf(pv[3].z); go[2] = rintf(gv[3].z);
        dx = pv[0].w - gv[0].w; dy = pv[1].w - gv[1].w; dz = pv[2].w - gv[2].w;
        dn[3] = sqrtf(dx*dx + dy*dy + dz*dz); po[3] = rintf(pv[3].w); go[3] = rintf(gv[3].w);
    }

    // acc[n]: {sim_sum, inter, gt_sum, s_sum}; count via ballot (scalar pipe)
    float acc[Nc][4];
    int   wcnt[Nc];
#pragma unroll
    for (int n = 0; n < Nc; ++n) {
        wcnt[n] = 0;
#pragma unroll
        for (int q = 0; q < 4; ++q) acc[n][q] = 0.f;
    }

#define PROC(n_, c_) do {                                                \
        asm volatile("s_waitcnt vmcnt(" #c_ ")" ::: "memory");           \
        __builtin_amdgcn_sched_barrier(0);                               \
        const int pmx[4] = {pmv[n_].x, pmv[n_].y, pmv[n_].z, pmv[n_].w}; \
        const int gmx[4] = {gmv[n_].x, gmv[n_].y, gmv[n_].z, gmv[n_].w}; \
        _Pragma("unroll")                                                \
        for (int j = 0; j < 4; ++j) {                                    \
            const bool P = pmx[j] != 0;                                  \
            const bool G = gmx[j] != 0;                                  \
            wcnt[n_] += __popcll(__ballot(P));                           \
            const float s = P ? po[j] : 0.f;                             \
            acc[n_][0] += P ? dn[j] : 0.f;                               \
            acc[n_][1] += G ? s     : 0.f;   /* inter = (P&&G)?po:0 */   \
            acc[n_][2] += G ? go[j] : 0.f;                               \
            acc[n_][3] += s;                 /* xor = s_sum - inter  */  \
        }                                                                \
    } while (0)

    PROC(0, 14); PROC(1, 12); PROC(2, 10); PROC(3, 8);
    PROC(4, 6);  PROC(5, 4);  PROC(6, 2);  PROC(7, 0);
#undef PROC

    // ---- LDS-transpose block reduction ----
    __shared__ float tr[256][33];    // stride 33: conflict-free both phases
    __shared__ float part[4][32];
    __shared__ float cpart[4][Nc];

#pragma unroll
    for (int qi = 0; qi < 32; ++qi) tr[tid][qi] = acc[qi >> 2][qi & 3];
    if (lane == 0) {
#pragma unroll
        for (int n = 0; n < Nc; ++n) cpart[wv][n] = (float)wcnt[n];
    }
    __syncthreads();

    {
        const int q    = tid & 31;   // quantity (n*4 + {sim,inter,gt,s})
        const int half = tid >> 5;   // chunk of 32 rows
        float s = 0.f;
#pragma unroll
        for (int k = 0; k < 32; ++k) s += tr[half * 32 + k][q];
        s += __shfl_xor(s, 32, 64);
        if ((tid & 32) == 0) part[tid >> 6][q] = s;
    }
    __syncthreads();

    if (tid < 32) {
        const float v = part[0][tid] + part[1][tid] + part[2][tid] + part[3][tid];
        const int n = tid >> 2, qq = tid & 3;
        const int slot = n * 5 + (qq == 0 ? 0 : qq + 1);  // sim->0 inter->2 gt->3 s->4
        atomicAdd(&ws[(b * 40 + slot) * PAD], v);
    } else if (tid >= 64 && tid < 64 + Nc) {
        const int n = tid - 64;
        const float c = cpart[0][n] + cpart[1][n] + cpart[2][n] + cpart[3][n];
        atomicAdd(&ws[(b * 40 + n * 5 + 1) * PAD], c);
    }
}

__global__ __launch_bounds__(64) void niou_final(
    const float* __restrict__ ws, float* __restrict__ out)
{
    const int t = threadIdx.x;   // 0..63 == b*8+n
    const float* w = ws + (size_t)t * 5 * PAD;
    const float sim   = w[0 * PAD];
    const float cnt   = w[1 * PAD];
    const float inter = w[2 * PAD];
    const float gts   = w[3 * PAD];
    const float ssum  = w[4 * PAD];
    const float xo    = ssum - inter;            // pd_xor_sum
    const float punish = sim / (cnt + EPSc);
    const float iou    = inter / (gts + xo + EPSc);
    float term = 1.0f - iou + punish;
#pragma unroll
    for (int off = 32; off; off >>= 1) term += __shfl_xor(term, off, 64);
    if (t == 0) out[0] = term * (1.0f / 64.0f);
}

extern "C" void kernel_launch(void* const* d_in, const int* in_sizes, int n_in,
                              void* d_out, int out_size, void* d_ws, size_t ws_size,
                              hipStream_t stream) {
    const float* pd_rgbo = (const float*)d_in[0];
    const float* gt_rgbo = (const float*)d_in[1];
    const int*   pd_mask = (const int*)d_in[2];
    const int*   gt_mask = (const int*)d_in[3];
    float* out = (float*)d_out;
    float* ws  = (float*)d_ws;

    hipMemsetAsync(ws, 0, Bc * 40 * PAD * sizeof(float), stream);
    niou_partial<<<Bc * 256, 256, 0, stream>>>(pd_rgbo, gt_rgbo, pd_mask, gt_mask, ws);
    niou_final<<<1, 64, 0, stream>>>(ws, out);
}